// Round 6
// baseline (138.436 us; speedup 1.0000x reference)
//
#include <hip/hip_runtime.h>
#include <math.h>

// Problem constants (from reference setup_inputs)
#define B 8
#define S 512
#define G 16
#define DA 1024
#define DM 256
#define WIN 12
#define NCH 64                    // s-chunks for partial max/sum
#define RPC (S / NCH)             // 8 rows per chunk
#define DTOT (DA + DM)            // 1280 pooled dims
#define NW 8                      // waves per block (512 threads)
#define NSWEEP (NCH * B)          // 512 sweep blocks
#define NWIN (B * (G - 1))        // 120 window blocks
#define NBLK (NSWEEP + NWIN + B)  // +8 g0 blocks (placed last)

__inline__ __device__ float4 fmax4(float4 a, float4 b) {
    return make_float4(fmaxf(a.x, b.x), fmaxf(a.y, b.y),
                       fmaxf(a.z, b.z), fmaxf(a.w, b.w));
}
__inline__ __device__ float4 add4(float4 a, float4 b) {
    return make_float4(a.x + b.x, a.y + b.y, a.z + b.z, a.w + b.w);
}
__inline__ __device__ float dot4(float4 a, float4 b) {
    return a.x * b.x + a.y * b.y + a.z * b.z + a.w * b.w;
}

// 8-wave (512-thread) batched block reduce: 4 sums in one LDS round.
__inline__ __device__ float4 blockReduceSum4_8(float4 v, float4* sh) {
    int lane = threadIdx.x & 63, w = threadIdx.x >> 6;
#pragma unroll
    for (int o = 32; o > 0; o >>= 1) {
        v.x += __shfl_xor(v.x, o, 64);
        v.y += __shfl_xor(v.y, o, 64);
        v.z += __shfl_xor(v.z, o, 64);
        v.w += __shfl_xor(v.w, o, 64);
    }
    __syncthreads();
    if (lane == 0) sh[w] = v;
    __syncthreads();
    float4 r = sh[0];
#pragma unroll
    for (int ww = 1; ww < NW; ++ww) {
        r.x += sh[ww].x; r.y += sh[ww].y; r.z += sh[ww].z; r.w += sh[ww].w;
    }
    return r;
}

// Single fused kernel, one dispatch:
//  blocks [0, 512):        sweep -> pmax/psum per (b, chunk, d); release cnt[b]
//  blocks [512, 632):      window logits g>=1 (independent of sweep)
//  blocks [632, 640):      g==0 logits; acquire-spin until cnt[b]==NCH
__global__ __launch_bounds__(512) void k_all(
    const float* __restrict__ att, const float* __restrict__ mod,
    const float* __restrict__ Wa, const float* __restrict__ Wm,
    const float* __restrict__ ba, const float* __restrict__ bm,
    const int* __restrict__ gidx, const int* __restrict__ mask,
    float* __restrict__ pmax, float* __restrict__ psum,
    int* __restrict__ cnt, float* __restrict__ out)
{
    __shared__ float part[NW][DTOT];   // 40 KB, reused by all paths
    __shared__ float4 s4[NW];
    const int bid = blockIdx.x;
    const int t = threadIdx.x, lane = t & 63, w = t >> 6;

    const float4* att4 = (const float4*)att;
    const float4* mod4 = (const float4*)mod;

    if (bid < NSWEEP) {
        // ---------------- sweep: per-chunk per-d max AND sum ----------------
        const int ch = bid & (NCH - 1), b = bid >> 6;
        const int row = b * S + ch * RPC + w;   // wave w owns one row

        float4* pr = (float4*)&part[w][0];
        const float4* arow = att4 + (size_t)row * (DA / 4);
#pragma unroll
        for (int k = 0; k < 4; ++k) pr[lane + 64 * k] = arow[lane + 64 * k];
        ((float4*)&part[w][DA])[lane] = mod4[(size_t)row * (DM / 4) + lane];
        __syncthreads();

        const size_t base = ((size_t)b * NCH + ch) * DTOT;
        for (int d = t; d < DTOT; d += 512) {
            float v0 = part[0][d];
            float mx = v0, sm = v0;
#pragma unroll
            for (int ww = 1; ww < NW; ++ww) {
                float v = part[ww][d];
                mx = fmaxf(mx, v);
                sm += v;
            }
            pmax[base + d] = mx;
            psum[base + d] = sm;
        }
        __threadfence();
        __syncthreads();
        if (t == 0)
            __hip_atomic_fetch_add(&cnt[b], 1, __ATOMIC_RELEASE,
                                   __HIP_MEMORY_SCOPE_AGENT);
    } else if (bid < NSWEEP + NWIN) {
        // ---------------- window logit g>=1 (independent) -------------------
        const int idx = bid - NSWEEP;
        const int b = idx / (G - 1), g = 1 + idx % (G - 1);
        const int gi = gidx[b * G + g];
        int lo = gi - WIN; if (lo < 0) lo = 0;
        int hi = gi + WIN; if (hi > S - 1) hi = S - 1;

        // Per-d windowed masked max (clamped at 0 by the reference's x*wmf
        // form; window <= 25 < 512 rows always leaves zeros) and masked sum.
        float4 amax2[4], asum2[4];
#pragma unroll
        for (int k = 0; k < 4; ++k) {
            amax2[k] = make_float4(0.f, 0.f, 0.f, 0.f);
            asum2[k] = make_float4(0.f, 0.f, 0.f, 0.f);
        }
        float4 mmax2 = make_float4(0.f, 0.f, 0.f, 0.f);
        float4 msum2 = make_float4(0.f, 0.f, 0.f, 0.f);
        float cn = 0.f;

        for (int s = lo + w; s <= hi; s += NW) {
            if (mask[b * S + s] > 0) {
                const int row = b * S + s;
                const float4* arow = att4 + (size_t)row * (DA / 4);
#pragma unroll
                for (int k = 0; k < 4; ++k) {
                    float4 v = arow[lane + 64 * k];
                    amax2[k] = fmax4(amax2[k], v);
                    asum2[k] = add4(asum2[k], v);
                }
                float4 vm = mod4[(size_t)row * (DM / 4) + lane];
                mmax2 = fmax4(mmax2, vm);
                msum2 = add4(msum2, vm);
                if (lane == 0) cn += 1.f;
            }
        }

        float4* pr = (float4*)&part[w][0];

        // Pass 1: merge maxes, dot with max-slice weights.
#pragma unroll
        for (int k = 0; k < 4; ++k) pr[lane + 64 * k] = amax2[k];
        ((float4*)&part[w][DA])[lane] = mmax2;
        __syncthreads();
        float wdot1 = 0.f;
        for (int d = t; d < DTOT; d += 512) {
            float mx = part[0][d];
#pragma unroll
            for (int ww = 1; ww < NW; ++ww) mx = fmaxf(mx, part[ww][d]);
            float wgt = (d < DA) ? Wa[DA + d] : Wm[DM + (d - DA)];
            wdot1 += wgt * mx;
        }
        __syncthreads();

        // Pass 2: merge sums, dot with avg-slice weights.
#pragma unroll
        for (int k = 0; k < 4; ++k) pr[lane + 64 * k] = asum2[k];
        ((float4*)&part[w][DA])[lane] = msum2;
        __syncthreads();
        float wdot2 = 0.f;
        for (int d = t; d < DTOT; d += 512) {
            float sm = part[0][d];
#pragma unroll
            for (int ww = 1; ww < NW; ++ww) sm += part[ww][d];
            float wgt = (d < DA) ? Wa[2 * DA + d] : Wm[2 * DM + (d - DA)];
            wdot2 += wgt * sm;
        }

        // Center-row gather dot: att[gi]·W0a + mod[gi]·W0m.
        float cd = 0.f;
        if (t < 256)
            cd = dot4(att4[(size_t)(b * S + gi) * (DA / 4) + t],
                      ((const float4*)Wa)[t]);
        else if (t < 256 + DM / 4)
            cd = dot4(mod4[(size_t)(b * S + gi) * (DM / 4) + (t - 256)],
                      ((const float4*)Wm)[t - 256]);

        float4 r = blockReduceSum4_8(make_float4(wdot1, wdot2, cd, cn), s4);
        if (t == 0)
            out[b * G + g] = r.z + r.x + r.y / r.w + ba[0] + bm[0];
    } else {
        // ---------------- g==0 logit: global pools from chunk partials ------
        const int b = bid - NSWEEP - NWIN;
        if (t == 0) {
            while (__hip_atomic_load(&cnt[b], __ATOMIC_ACQUIRE,
                                     __HIP_MEMORY_SCOPE_AGENT) < NCH) {}
        }
        __syncthreads();
        __threadfence();

        float gd1 = 0.f, gd2 = 0.f;
        for (int d = t; d < DTOT; d += 512) {
            float mx = -INFINITY, sm = 0.f;
#pragma unroll 8
            for (int ch = 0; ch < NCH; ++ch) {
                const size_t o = ((size_t)b * NCH + ch) * DTOT + d;
                mx = fmaxf(mx, pmax[o]);
                sm += psum[o];
            }
            float wg1 = (d < DA) ? Wa[DA + d] : Wm[DM + (d - DA)];
            float wg2 = (d < DA) ? Wa[2 * DA + d] : Wm[2 * DM + (d - DA)];
            gd1 += wg1 * mx;
            gd2 += wg2 * sm;
        }
        float cm = 0.f;
        for (int s = t; s < S; s += 512) cm += (float)mask[b * S + s];

        const int gi = gidx[b * G + 0];
        float cd = 0.f;
        if (t < 256)
            cd = dot4(att4[(size_t)(b * S + gi) * (DA / 4) + t],
                      ((const float4*)Wa)[t]);
        else if (t < 256 + DM / 4)
            cd = dot4(mod4[(size_t)(b * S + gi) * (DM / 4) + (t - 256)],
                      ((const float4*)Wm)[t - 256]);

        float4 r = blockReduceSum4_8(make_float4(gd1, gd2, cd, cm), s4);
        if (t == 0)
            out[b * G + 0] = r.z + r.x + r.y / r.w + ba[0] + bm[0];
    }
}

extern "C" void kernel_launch(void* const* d_in, const int* in_sizes, int n_in,
                              void* d_out, int out_size, void* d_ws, size_t ws_size,
                              hipStream_t stream) {
    const float* att  = (const float*)d_in[0];
    const float* mod  = (const float*)d_in[1];
    const float* Wa   = (const float*)d_in[2];
    const float* ba   = (const float*)d_in[3];
    const float* Wm   = (const float*)d_in[4];
    const float* bm   = (const float*)d_in[5];
    // d_in[6] = q_enc (unused by reference)
    const int* gidx   = (const int*)d_in[7];
    const int* mask   = (const int*)d_in[8];
    // d_in[9] = q_mask (unused by reference)
    float* out = (float*)d_out;

    // Workspace layout (floats)
    float* ws   = (float*)d_ws;
    float* pmax = ws;                         // B*NCH*DTOT = 655360
    float* psum = pmax + (size_t)B * NCH * DTOT;
    int*   cnt  = (int*)(psum + (size_t)B * NCH * DTOT);   // B ints

    hipMemsetAsync(cnt, 0, B * sizeof(int), stream);
    k_all<<<NBLK, 512, 0, stream>>>(att, mod, Wa, Wm, ba, bm, gidx, mask,
                                    pmax, psum, cnt, out);
}

// Round 7
// 38.649 us; speedup vs baseline: 3.5819x; 3.5819x over previous
//
#include <hip/hip_runtime.h>
#include <math.h>

// Problem constants (from reference setup_inputs)
#define B 8
#define S 512
#define G 16
#define DA 1024
#define DM 256
#define WIN 12
#define NCH 128                   // s-chunks per batch for partial max/sum
#define RPC (S / NCH)             // 4 rows per chunk
#define DTOT (DA + DM)            // 1280 pooled dims
#define WPB1 4                    // waves per K1 block (256 threads)
#define NBLK1 (B * NCH / WPB1)    // 256 sweep blocks

__inline__ __device__ float4 fmax4(float4 a, float4 b) {
    return make_float4(fmaxf(a.x, b.x), fmaxf(a.y, b.y),
                       fmaxf(a.z, b.z), fmaxf(a.w, b.w));
}
__inline__ __device__ float4 add4(float4 a, float4 b) {
    return make_float4(a.x + b.x, a.y + b.y, a.z + b.z, a.w + b.w);
}
__inline__ __device__ float dot4(float4 a, float4 b) {
    return a.x * b.x + a.y * b.y + a.z * b.z + a.w * b.w;
}

// 8-wave (512-thread) batched block reduce: 4 sums in one LDS round.
__inline__ __device__ float4 blockReduceSum4_8(float4 v, float4* sh) {
    int lane = threadIdx.x & 63, w = threadIdx.x >> 6;
#pragma unroll
    for (int o = 32; o > 0; o >>= 1) {
        v.x += __shfl_xor(v.x, o, 64);
        v.y += __shfl_xor(v.y, o, 64);
        v.z += __shfl_xor(v.z, o, 64);
        v.w += __shfl_xor(v.w, o, 64);
    }
    __syncthreads();
    if (lane == 0) sh[w] = v;
    __syncthreads();
    float4 r = sh[0];
#pragma unroll
    for (int ww = 1; ww < 8; ++ww) {
        r.x += sh[ww].x; r.y += sh[ww].y; r.z += sh[ww].z; r.w += sh[ww].w;
    }
    return r;
}

// K1: pure-streaming sweep. Each wave owns one chunk of RPC=4 contiguous
// rows; accumulates per-d max AND sum in registers; writes partials.
// No LDS, no shuffles, no __syncthreads.
__global__ __launch_bounds__(256) void k_sweep(
    const float* __restrict__ att, const float* __restrict__ mod,
    float* __restrict__ pmax, float* __restrict__ psum)
{
    const int t = threadIdx.x, lane = t & 63, w = t >> 6;
    const int chunkId = blockIdx.x * WPB1 + w;          // 0 .. B*NCH-1
    const int b = chunkId >> 7;                          // / NCH
    const int ch = chunkId & (NCH - 1);
    const int row0 = b * S + ch * RPC;

    const float4* att4 = (const float4*)att;
    const float4* mod4 = (const float4*)mod;

    float4 amax[4], asum[4];
#pragma unroll
    for (int k = 0; k < 4; ++k) {
        amax[k] = make_float4(-INFINITY, -INFINITY, -INFINITY, -INFINITY);
        asum[k] = make_float4(0.f, 0.f, 0.f, 0.f);
    }
    float4 mmax = make_float4(-INFINITY, -INFINITY, -INFINITY, -INFINITY);
    float4 msum = make_float4(0.f, 0.f, 0.f, 0.f);

#pragma unroll
    for (int r = 0; r < RPC; ++r) {
        const float4* arow = att4 + (size_t)(row0 + r) * (DA / 4);
#pragma unroll
        for (int k = 0; k < 4; ++k) {
            float4 v = arow[lane + 64 * k];
            amax[k] = fmax4(amax[k], v);
            asum[k] = add4(asum[k], v);
        }
        float4 vm = mod4[(size_t)(row0 + r) * (DM / 4) + lane];
        mmax = fmax4(mmax, vm);
        msum = add4(msum, vm);
    }

    const size_t base = ((size_t)b * NCH + ch) * DTOT;
    float4* pm4 = (float4*)(pmax + base);
    float4* ps4 = (float4*)(psum + base);
#pragma unroll
    for (int k = 0; k < 4; ++k) {
        pm4[lane + 64 * k] = amax[k];
        ps4[lane + 64 * k] = asum[k];
    }
    ((float4*)(pmax + base + DA))[lane] = mmax;
    ((float4*)(psum + base + DA))[lane] = msum;
}

// K2: one 512-thread block per logit. g>=1 from raw windows (L3-warm);
// g==0 from K1's partials (kernel boundary = the barrier).
__global__ __launch_bounds__(512) void k_logits(
    const float* __restrict__ att, const float* __restrict__ mod,
    const float* __restrict__ Wa, const float* __restrict__ Wm,
    const float* __restrict__ ba, const float* __restrict__ bm,
    const int* __restrict__ gidx, const int* __restrict__ mask,
    const float* __restrict__ pmax, const float* __restrict__ psum,
    float* __restrict__ out)
{
    __shared__ float part[8][DTOT];   // 40 KB
    __shared__ float4 s4[8];
    const int g = blockIdx.x, b = blockIdx.y;
    const int t = threadIdx.x, lane = t & 63, w = t >> 6;
    const int gi = gidx[b * G + g];

    const float4* att4 = (const float4*)att;
    const float4* mod4 = (const float4*)mod;

    // Center-row gather dot: att[gi]·W0a + mod[gi]·W0m (all g).
    float cd = 0.f;
    if (t < 256)
        cd = dot4(att4[(size_t)(b * S + gi) * (DA / 4) + t],
                  ((const float4*)Wa)[t]);
    else if (t < 256 + DM / 4)
        cd = dot4(mod4[(size_t)(b * S + gi) * (DM / 4) + (t - 256)],
                  ((const float4*)Wm)[t - 256]);

    if (g == 0) {
        // Global pools from chunk partials.
        float gd1 = 0.f, gd2 = 0.f;
        for (int d = t; d < DTOT; d += 512) {
            float mx = -INFINITY, sm = 0.f;
#pragma unroll 8
            for (int ch = 0; ch < NCH; ++ch) {
                const size_t o = ((size_t)b * NCH + ch) * DTOT + d;
                mx = fmaxf(mx, pmax[o]);
                sm += psum[o];
            }
            float wg1 = (d < DA) ? Wa[DA + d] : Wm[DM + (d - DA)];
            float wg2 = (d < DA) ? Wa[2 * DA + d] : Wm[2 * DM + (d - DA)];
            gd1 += wg1 * mx;
            gd2 += wg2 * sm;
        }
        float cm = 0.f;
        for (int s = t; s < S; s += 512) cm += (float)mask[b * S + s];

        float4 r = blockReduceSum4_8(make_float4(gd1, gd2, cd, cm), s4);
        if (t == 0)
            out[b * G + 0] = r.z + r.x + r.y / r.w + ba[0] + bm[0];
    } else {
        int lo = gi - WIN; if (lo < 0) lo = 0;
        int hi = gi + WIN; if (hi > S - 1) hi = S - 1;

        // Per-d windowed masked max (clamped at 0 by the reference's x*wmf
        // form; window <= 25 < 512 rows always leaves zeros) and masked sum.
        float4 amax2[4], asum2[4];
#pragma unroll
        for (int k = 0; k < 4; ++k) {
            amax2[k] = make_float4(0.f, 0.f, 0.f, 0.f);
            asum2[k] = make_float4(0.f, 0.f, 0.f, 0.f);
        }
        float4 mmax2 = make_float4(0.f, 0.f, 0.f, 0.f);
        float4 msum2 = make_float4(0.f, 0.f, 0.f, 0.f);
        float cn = 0.f;

        for (int s = lo + w; s <= hi; s += 8) {
            if (mask[b * S + s] > 0) {
                const int row = b * S + s;
                const float4* arow = att4 + (size_t)row * (DA / 4);
#pragma unroll
                for (int k = 0; k < 4; ++k) {
                    float4 v = arow[lane + 64 * k];
                    amax2[k] = fmax4(amax2[k], v);
                    asum2[k] = add4(asum2[k], v);
                }
                float4 vm = mod4[(size_t)row * (DM / 4) + lane];
                mmax2 = fmax4(mmax2, vm);
                msum2 = add4(msum2, vm);
                if (lane == 0) cn += 1.f;
            }
        }

        float4* pr = (float4*)&part[w][0];

        // Pass 1: merge maxes, dot with max-slice weights.
#pragma unroll
        for (int k = 0; k < 4; ++k) pr[lane + 64 * k] = amax2[k];
        ((float4*)&part[w][DA])[lane] = mmax2;
        __syncthreads();
        float wdot1 = 0.f;
        for (int d = t; d < DTOT; d += 512) {
            float mx = part[0][d];
#pragma unroll
            for (int ww = 1; ww < 8; ++ww) mx = fmaxf(mx, part[ww][d]);
            float wgt = (d < DA) ? Wa[DA + d] : Wm[DM + (d - DA)];
            wdot1 += wgt * mx;
        }
        __syncthreads();

        // Pass 2: merge sums, dot with avg-slice weights.
#pragma unroll
        for (int k = 0; k < 4; ++k) pr[lane + 64 * k] = asum2[k];
        ((float4*)&part[w][DA])[lane] = msum2;
        __syncthreads();
        float wdot2 = 0.f;
        for (int d = t; d < DTOT; d += 512) {
            float sm = part[0][d];
#pragma unroll
            for (int ww = 1; ww < 8; ++ww) sm += part[ww][d];
            float wgt = (d < DA) ? Wa[2 * DA + d] : Wm[2 * DM + (d - DA)];
            wdot2 += wgt * sm;
        }

        float4 r = blockReduceSum4_8(make_float4(wdot1, wdot2, cd, cn), s4);
        if (t == 0)
            out[b * G + g] = r.z + r.x + r.y / r.w + ba[0] + bm[0];
    }
}

extern "C" void kernel_launch(void* const* d_in, const int* in_sizes, int n_in,
                              void* d_out, int out_size, void* d_ws, size_t ws_size,
                              hipStream_t stream) {
    const float* att  = (const float*)d_in[0];
    const float* mod  = (const float*)d_in[1];
    const float* Wa   = (const float*)d_in[2];
    const float* ba   = (const float*)d_in[3];
    const float* Wm   = (const float*)d_in[4];
    const float* bm   = (const float*)d_in[5];
    // d_in[6] = q_enc (unused by reference)
    const int* gidx   = (const int*)d_in[7];
    const int* mask   = (const int*)d_in[8];
    // d_in[9] = q_mask (unused by reference)
    float* out = (float*)d_out;

    // Workspace layout (floats)
    float* ws   = (float*)d_ws;
    float* pmax = ws;                                   // B*NCH*DTOT
    float* psum = pmax + (size_t)B * NCH * DTOT;        // B*NCH*DTOT

    k_sweep<<<NBLK1, 256, 0, stream>>>(att, mod, pmax, psum);
    k_logits<<<dim3(G, B), 512, 0, stream>>>(att, mod, Wa, Wm, ba, bm,
                                             gidx, mask, pmax, psum, out);
}

// Round 8
// 19.200 us; speedup vs baseline: 7.2101x; 2.0129x over previous
//
#include <hip/hip_runtime.h>
#include <math.h>

// Problem constants (from reference setup_inputs)
#define B 8
#define S 512
#define G 16
#define DA 1024
#define DM 256
#define WIN 12
#define NCH 32                    // s-chunks per batch for partial max/sum
#define RPC (S / NCH)             // 16 rows per chunk
#define DTOT (DA + DM)            // 1280 pooled dims
#define NW 8                      // waves per block (512 threads)
#define RPW (RPC / NW)            // 2 rows per wave in the sweep

__inline__ __device__ float4 fmax4(float4 a, float4 b) {
    return make_float4(fmaxf(a.x, b.x), fmaxf(a.y, b.y),
                       fmaxf(a.z, b.z), fmaxf(a.w, b.w));
}
__inline__ __device__ float4 add4(float4 a, float4 b) {
    return make_float4(a.x + b.x, a.y + b.y, a.z + b.z, a.w + b.w);
}
__inline__ __device__ float dot4(float4 a, float4 b) {
    return a.x * b.x + a.y * b.y + a.z * b.z + a.w * b.w;
}

// 8-wave (512-thread) batched block reduce: 4 sums in one LDS round.
__inline__ __device__ float4 blockReduceSum4_8(float4 v, float4* sh) {
    int lane = threadIdx.x & 63, w = threadIdx.x >> 6;
#pragma unroll
    for (int o = 32; o > 0; o >>= 1) {
        v.x += __shfl_xor(v.x, o, 64);
        v.y += __shfl_xor(v.y, o, 64);
        v.z += __shfl_xor(v.z, o, 64);
        v.w += __shfl_xor(v.w, o, 64);
    }
    __syncthreads();
    if (lane == 0) sh[w] = v;
    __syncthreads();
    float4 r = sh[0];
#pragma unroll
    for (int ww = 1; ww < 8; ++ww) {
        r.x += sh[ww].x; r.y += sh[ww].y; r.z += sh[ww].z; r.w += sh[ww].w;
    }
    return r;
}

// K1: streaming sweep, grid (NCH, B) = 256 blocks x 512 threads (8 waves/CU).
// Wave w owns rows [ch*RPC + 2w, ch*RPC + 2w + 1]; accumulates per-d max AND
// sum in registers (no shuffles, no proj stores), then one LDS merge writes
// the per-(b,chunk,d) partials. 80 KB LDS -> 1 block/CU.
__global__ __launch_bounds__(512) void k_sweep(
    const float* __restrict__ att, const float* __restrict__ mod,
    float* __restrict__ pmax, float* __restrict__ psum)
{
    __shared__ float partM[NW][DTOT];   // 40 KB
    __shared__ float partS[NW][DTOT];   // 40 KB
    const int ch = blockIdx.x, b = blockIdx.y;
    const int t = threadIdx.x, lane = t & 63, w = t >> 6;

    const float4* att4 = (const float4*)att;
    const float4* mod4 = (const float4*)mod;

    float4 amax[4], asum[4];
#pragma unroll
    for (int k = 0; k < 4; ++k) {
        amax[k] = make_float4(-INFINITY, -INFINITY, -INFINITY, -INFINITY);
        asum[k] = make_float4(0.f, 0.f, 0.f, 0.f);
    }
    float4 mmax = make_float4(-INFINITY, -INFINITY, -INFINITY, -INFINITY);
    float4 msum = make_float4(0.f, 0.f, 0.f, 0.f);

    const int row0 = b * S + ch * RPC + w * RPW;
#pragma unroll
    for (int r = 0; r < RPW; ++r) {
        const float4* arow = att4 + (size_t)(row0 + r) * (DA / 4);
#pragma unroll
        for (int k = 0; k < 4; ++k) {
            float4 v = arow[lane + 64 * k];
            amax[k] = fmax4(amax[k], v);
            asum[k] = add4(asum[k], v);
        }
        float4 vm = mod4[(size_t)(row0 + r) * (DM / 4) + lane];
        mmax = fmax4(mmax, vm);
        msum = add4(msum, vm);
    }

    // Publish per-wave partials: att d = 4*(lane+64k)+{0..3}, mod at DA+4*lane.
    float4* pm = (float4*)&partM[w][0];
    float4* ps = (float4*)&partS[w][0];
#pragma unroll
    for (int k = 0; k < 4; ++k) {
        pm[lane + 64 * k] = amax[k];
        ps[lane + 64 * k] = asum[k];
    }
    ((float4*)&partM[w][DA])[lane] = mmax;
    ((float4*)&partS[w][DA])[lane] = msum;
    __syncthreads();

    // Cross-wave merge; stride 1280 ≡ 0 mod 32 banks -> conflict-free.
    const size_t base = ((size_t)b * NCH + ch) * DTOT;
    for (int d = t; d < DTOT; d += 512) {
        float mx = partM[0][d], sm = partS[0][d];
#pragma unroll
        for (int ww = 1; ww < NW; ++ww) {
            mx = fmaxf(mx, partM[ww][d]);
            sm += partS[ww][d];
        }
        pmax[base + d] = mx;
        psum[base + d] = sm;
    }
}

// K2: one 512-thread block per logit. g>=1 from raw windows (L3-warm);
// g==0 from K1's partials (kernel boundary = the barrier).
__global__ __launch_bounds__(512) void k_logits(
    const float* __restrict__ att, const float* __restrict__ mod,
    const float* __restrict__ Wa, const float* __restrict__ Wm,
    const float* __restrict__ ba, const float* __restrict__ bm,
    const int* __restrict__ gidx, const int* __restrict__ mask,
    const float* __restrict__ pmax, const float* __restrict__ psum,
    float* __restrict__ out)
{
    __shared__ float part[8][DTOT];   // 40 KB
    __shared__ float4 s4[8];
    const int g = blockIdx.x, b = blockIdx.y;
    const int t = threadIdx.x, lane = t & 63, w = t >> 6;
    const int gi = gidx[b * G + g];

    const float4* att4 = (const float4*)att;
    const float4* mod4 = (const float4*)mod;

    // Center-row gather dot: att[gi]·W0a + mod[gi]·W0m (all g).
    float cd = 0.f;
    if (t < 256)
        cd = dot4(att4[(size_t)(b * S + gi) * (DA / 4) + t],
                  ((const float4*)Wa)[t]);
    else if (t < 256 + DM / 4)
        cd = dot4(mod4[(size_t)(b * S + gi) * (DM / 4) + (t - 256)],
                  ((const float4*)Wm)[t - 256]);

    if (g == 0) {
        // Global pools from chunk partials (32-deep merge).
        float gd1 = 0.f, gd2 = 0.f;
        for (int d = t; d < DTOT; d += 512) {
            float mx = -INFINITY, sm = 0.f;
#pragma unroll 8
            for (int ch = 0; ch < NCH; ++ch) {
                const size_t o = ((size_t)b * NCH + ch) * DTOT + d;
                mx = fmaxf(mx, pmax[o]);
                sm += psum[o];
            }
            float wg1 = (d < DA) ? Wa[DA + d] : Wm[DM + (d - DA)];
            float wg2 = (d < DA) ? Wa[2 * DA + d] : Wm[2 * DM + (d - DA)];
            gd1 += wg1 * mx;
            gd2 += wg2 * sm;
        }
        float cm = 0.f;
        for (int s = t; s < S; s += 512) cm += (float)mask[b * S + s];

        float4 r = blockReduceSum4_8(make_float4(gd1, gd2, cd, cm), s4);
        if (t == 0)
            out[b * G + 0] = r.z + r.x + r.y / r.w + ba[0] + bm[0];
    } else {
        int lo = gi - WIN; if (lo < 0) lo = 0;
        int hi = gi + WIN; if (hi > S - 1) hi = S - 1;

        // Per-d windowed masked max (clamped at 0 by the reference's x*wmf
        // form; window <= 25 < 512 rows always leaves zeros) and masked sum.
        float4 amax2[4], asum2[4];
#pragma unroll
        for (int k = 0; k < 4; ++k) {
            amax2[k] = make_float4(0.f, 0.f, 0.f, 0.f);
            asum2[k] = make_float4(0.f, 0.f, 0.f, 0.f);
        }
        float4 mmax2 = make_float4(0.f, 0.f, 0.f, 0.f);
        float4 msum2 = make_float4(0.f, 0.f, 0.f, 0.f);
        float cn = 0.f;

        for (int s = lo + w; s <= hi; s += 8) {
            if (mask[b * S + s] > 0) {
                const int row = b * S + s;
                const float4* arow = att4 + (size_t)row * (DA / 4);
#pragma unroll
                for (int k = 0; k < 4; ++k) {
                    float4 v = arow[lane + 64 * k];
                    amax2[k] = fmax4(amax2[k], v);
                    asum2[k] = add4(asum2[k], v);
                }
                float4 vm = mod4[(size_t)row * (DM / 4) + lane];
                mmax2 = fmax4(mmax2, vm);
                msum2 = add4(msum2, vm);
                if (lane == 0) cn += 1.f;
            }
        }

        float4* pr = (float4*)&part[w][0];

        // Pass 1: merge maxes, dot with max-slice weights.
#pragma unroll
        for (int k = 0; k < 4; ++k) pr[lane + 64 * k] = amax2[k];
        ((float4*)&part[w][DA])[lane] = mmax2;
        __syncthreads();
        float wdot1 = 0.f;
        for (int d = t; d < DTOT; d += 512) {
            float mx = part[0][d];
#pragma unroll
            for (int ww = 1; ww < 8; ++ww) mx = fmaxf(mx, part[ww][d]);
            float wgt = (d < DA) ? Wa[DA + d] : Wm[DM + (d - DA)];
            wdot1 += wgt * mx;
        }
        __syncthreads();

        // Pass 2: merge sums, dot with avg-slice weights.
#pragma unroll
        for (int k = 0; k < 4; ++k) pr[lane + 64 * k] = asum2[k];
        ((float4*)&part[w][DA])[lane] = msum2;
        __syncthreads();
        float wdot2 = 0.f;
        for (int d = t; d < DTOT; d += 512) {
            float sm = part[0][d];
#pragma unroll
            for (int ww = 1; ww < 8; ++ww) sm += part[ww][d];
            float wgt = (d < DA) ? Wa[2 * DA + d] : Wm[2 * DM + (d - DA)];
            wdot2 += wgt * sm;
        }

        float4 r = blockReduceSum4_8(make_float4(wdot1, wdot2, cd, cn), s4);
        if (t == 0)
            out[b * G + g] = r.z + r.x + r.y / r.w + ba[0] + bm[0];
    }
}

extern "C" void kernel_launch(void* const* d_in, const int* in_sizes, int n_in,
                              void* d_out, int out_size, void* d_ws, size_t ws_size,
                              hipStream_t stream) {
    const float* att  = (const float*)d_in[0];
    const float* mod  = (const float*)d_in[1];
    const float* Wa   = (const float*)d_in[2];
    const float* ba   = (const float*)d_in[3];
    const float* Wm   = (const float*)d_in[4];
    const float* bm   = (const float*)d_in[5];
    // d_in[6] = q_enc (unused by reference)
    const int* gidx   = (const int*)d_in[7];
    const int* mask   = (const int*)d_in[8];
    // d_in[9] = q_mask (unused by reference)
    float* out = (float*)d_out;

    // Workspace layout (floats)
    float* ws   = (float*)d_ws;
    float* pmax = ws;                                   // B*NCH*DTOT
    float* psum = pmax + (size_t)B * NCH * DTOT;        // B*NCH*DTOT

    k_sweep<<<dim3(NCH, B), 512, 0, stream>>>(att, mod, pmax, psum);
    k_logits<<<dim3(G, B), 512, 0, stream>>>(att, mod, Wa, Wm, ba, bm,
                                             gidx, mask, pmax, psum, out);
}